// Round 4
// baseline (501.711 us; speedup 1.0000x reference)
//
#include <hip/hip_runtime.h>

typedef unsigned short u16;
typedef unsigned int u32;
typedef u16 u16x4 __attribute__((ext_vector_type(4)));
typedef u16 u16x8 __attribute__((ext_vector_type(8)));
typedef float f32x4 __attribute__((ext_vector_type(4)));
typedef __bf16 bf16x8 __attribute__((ext_vector_type(8)));

#define DD 2048
#define SCALE_ATTN 0.08838834764831845f
#define DELTA 0.025f

// async global->LDS, 16B per lane, wave-uniform LDS base (HW: base + lane*16)
#define GL16(g, l)                                                              \
  __builtin_amdgcn_global_load_lds((const __attribute__((address_space(1))) u32*)(g), \
                                   (__attribute__((address_space(3))) u32*)(l), 16, 0, 0)

__device__ __forceinline__ u16 f2bf(float f) {
  u32 u = __float_as_uint(f);
  u32 r = (u + 0x7FFFu + ((u >> 16) & 1u)) >> 16;
  return (u16)r;
}
__device__ __forceinline__ float bf2f(u16 h) { return __uint_as_float(((u32)h) << 16); }

// ---------------- prep kernels ----------------

__global__ void k_rope_tables(float* __restrict__ cosT, float* __restrict__ sinT) {
  int i = blockIdx.x * 256 + threadIdx.x;  // < 2048*64
  int s = i >> 6, j = i & 63;
  float e = (float)(2 * j) / 128.0f;
  float inv = 1.0f / powf(10000.0f, e);
  float fr = (float)s * inv;
  cosT[i] = cosf(fr);
  sinT[i] = sinf(fr);
}

__global__ void k_split_x(const float* __restrict__ x, u16* __restrict__ xh, u16* __restrict__ xl) {
  int i = (blockIdx.x * 256 + threadIdx.x) * 4;
  float4 v = *(const float4*)&x[i];
  float vv[4] = {v.x, v.y, v.z, v.w};
  u16x4 ho, lo;
#pragma unroll
  for (int t = 0; t < 4; ++t) {
    u16 hb = f2bf(vv[t]);
    ho[t] = hb;
    lo[t] = f2bf(vv[t] - bf2f(hb));
  }
  *(u16x4*)&xh[i] = ho;
  *(u16x4*)&xl[i] = lo;
}

// W [k][n] fp32 -> WhT/WlT [n][k] bf16 (split). WlT may be null (Wo).
__global__ void k_transpose_split(const float* __restrict__ W, u16* __restrict__ WhT,
                                  u16* __restrict__ WlT) {
  __shared__ float tile[32][33];
  int bk = blockIdx.x & 63, bn = blockIdx.x >> 6;
  int c = threadIdx.x & 31, r0 = threadIdx.x >> 5;
#pragma unroll
  for (int i = 0; i < 4; ++i) {
    int r = r0 + i * 8;
    tile[r][c] = W[(size_t)(bk * 32 + r) * DD + bn * 32 + c];
  }
  __syncthreads();
#pragma unroll
  for (int i = 0; i < 4; ++i) {
    int r = r0 + i * 8;
    float v = tile[c][r];  // = W[bk*32+c][bn*32+r]
    u16 hb = f2bf(v);
    size_t o = (size_t)(bn * 32 + r) * DD + bk * 32 + c;
    WhT[o] = hb;
    if (WlT) WlT[o] = f2bf(v - bf2f(hb));
  }
}

__global__ void k_transpose_bf16(const u16* __restrict__ in, u16* __restrict__ out) {
  __shared__ u16 tile[32][33];
  int bk = blockIdx.x & 63, bn = blockIdx.x >> 6;
  int c = threadIdx.x & 31, r0 = threadIdx.x >> 5;
#pragma unroll
  for (int i = 0; i < 4; ++i) {
    int r = r0 + i * 8;
    tile[r][c] = in[(size_t)(bk * 32 + r) * DD + bn * 32 + c];
  }
  __syncthreads();
#pragma unroll
  for (int i = 0; i < 4; ++i) {
    int r = r0 + i * 8;
    out[(size_t)(bn * 32 + r) * DD + bk * 32 + c] = tile[c][r];
  }
}

__global__ void k_rope_apply(const u16* __restrict__ sq, const u16* __restrict__ sk,
                             const float* __restrict__ cosT, const float* __restrict__ sinT,
                             u16* __restrict__ rq, u16* __restrict__ rk) {
  int i = blockIdx.x * 256 + threadIdx.x;  // < 2048*16*64
  int s = i >> 10;
  int rest = i & 1023;
  int h = rest >> 6, j = rest & 63;
  size_t base = (size_t)s * DD + h * 128 + j;
  float c = cosT[(s << 6) | j], sn = sinT[(s << 6) | j];
  float a = bf2f(sq[base]), b = bf2f(sq[base + 64]);
  rq[base] = f2bf(a * c - b * sn);
  rq[base + 64] = f2bf(b * c + a * sn);
  a = bf2f(sk[base]);
  b = bf2f(sk[base + 64]);
  rk[base] = f2bf(a * c - b * sn);
  rk[base + 64] = f2bf(b * c + a * sn);
}

// ---------------- QKV GEMM pass 1: u ~= xh @ WhT, spike + borderline flags ----
// Error vs exact fp32 x@W: missing xh*Wl + xl*Wh, rms ~3.2e-3. Elements with
// |u-1| < DELTA (=8.1 sigma) are flagged for exact recompute in k_fixup.
__global__ __launch_bounds__(256) void k_gemm_qkv(
    const u16* __restrict__ xh, const u16* __restrict__ BqT, const u16* __restrict__ BkT,
    const u16* __restrict__ BvT, u16* __restrict__ Sq, u16* __restrict__ Sk,
    u16* __restrict__ Sv, unsigned char* __restrict__ flagT) {
  __shared__ u16 lA[2 * 4096];
  __shared__ u16 lB[2 * 4096];

  const u16* BT = blockIdx.y == 0 ? BqT : (blockIdx.y == 1 ? BkT : BvT);
  u16* Out = blockIdx.y == 0 ? Sq : (blockIdx.y == 1 ? Sk : Sv);
  unsigned char* flT = flagT + (size_t)blockIdx.y * 4194304;  // [j][i] bytemap

  int bid = blockIdx.x;
  int swz = (bid & 7) * 32 + (bid >> 3);  // XCD-aware swizzle, 256 % 8 == 0
  int m0 = (swz >> 4) * 128, n0 = (swz & 15) * 128;

  int tid = threadIdx.x;
  int lane = tid & 63;
  int w = tid >> 6;
  int wr = (w >> 1) * 64, wc = (w & 1) * 64;
  int l15 = lane & 15, g8 = (lane >> 4) * 8;

  int ar0 = tid >> 2, ac0 = (tid & 3) << 3;          // rows 0..63
  int ar1 = (tid + 256) >> 2, ac1 = (tid & 3) << 3;  // rows 64..127

  f32x4 zero = {0.f, 0.f, 0.f, 0.f};
  f32x4 acc[4][4];
#pragma unroll
  for (int i = 0; i < 4; ++i)
#pragma unroll
    for (int j = 0; j < 4; ++j) acc[i][j] = zero;

  u16* laBase0 = lA + w * 512;
  u16* laBase1 = lA + 2048 + w * 512;
  u16* lbBase0 = lB + w * 512;
  u16* lbBase1 = lB + 2048 + w * 512;

  auto stage = [&](int buf, int vs) {
    int k0 = vs << 5;
    int bo = buf * 4096;
    GL16(&xh[(size_t)(m0 + ar0) * DD + k0 + ac0], laBase0 + bo);
    GL16(&xh[(size_t)(m0 + ar1) * DD + k0 + ac1], laBase1 + bo);
    GL16(&BT[(size_t)(n0 + ar0) * DD + k0 + ac0], lbBase0 + bo);
    GL16(&BT[(size_t)(n0 + ar1) * DD + k0 + ac1], lbBase1 + bo);
  };

  stage(0, 0);
  __syncthreads();  // prologue: buf0 ready
  for (int vs = 0; vs < 64; ++vs) {
    int cur = vs & 1;
    if (vs + 1 < 64) stage(cur ^ 1, vs + 1);  // issue next-tile loads FIRST
    const u16* la = lA + cur * 4096;
    const u16* lb = lB + cur * 4096;
    bf16x8 af[4], bfr[4];
#pragma unroll
    for (int i = 0; i < 4; ++i) af[i] = *(const bf16x8*)&la[(wr + i * 16 + l15) * 32 + g8];
#pragma unroll
    for (int j = 0; j < 4; ++j) bfr[j] = *(const bf16x8*)&lb[(wc + j * 16 + l15) * 32 + g8];
#pragma unroll
    for (int i = 0; i < 4; ++i)
#pragma unroll
      for (int j = 0; j < 4; ++j)
        acc[i][j] = __builtin_amdgcn_mfma_f32_16x16x32_bf16(af[i], bfr[j], acc[i][j], 0, 0, 0);
    __syncthreads();  // one vmcnt(0)+barrier per tile, at the END
  }

  int g4 = (lane >> 4) * 4;
#pragma unroll
  for (int i = 0; i < 4; ++i) {
    int row0 = m0 + wr + i * 16 + g4;
#pragma unroll
    for (int j = 0; j < 4; ++j) {
      int col = n0 + wc + j * 16 + l15;
      u32 fw = 0;
#pragma unroll
      for (int r = 0; r < 4; ++r) {
        float u = acc[i][j][r];
        Out[(size_t)(row0 + r) * DD + col] = (u > 1.0f) ? (u16)0x3F80 : (u16)0;
        if (fabsf(u - 1.0f) < DELTA) fw |= (1u << (8 * r));
      }
      *(u32*)&flT[(size_t)col * 2048 + row0] = fw;  // row0 % 4 == 0, aligned
    }
  }
}

// ---------------- fixup: exact recompute of borderline spikes ----------------
// Scan bytemap 64B/wave; for each flagged (mat,j,i) all 64 lanes do the exact
// fp32 dot u = sum_k (xh+xl)*(Wh+Wl) and overwrite the spike.
#define NCHUNK 196608  // 3*2048*2048/64
__global__ __launch_bounds__(256) void k_fixup(
    const u16* __restrict__ xh, const u16* __restrict__ xl, const u16* __restrict__ BqH,
    const u16* __restrict__ BqL, const u16* __restrict__ BkH, const u16* __restrict__ BkL,
    const u16* __restrict__ BvH, const u16* __restrict__ BvL,
    const unsigned char* __restrict__ flagT, u16* __restrict__ Sq, u16* __restrict__ Sk,
    u16* __restrict__ Sv) {
  int wid = (blockIdx.x * 256 + threadIdx.x) >> 6;
  int lane = threadIdx.x & 63;
  for (int c = wid; c < NCHUNK; c += 8192) {
    size_t base = (size_t)c << 6;
    unsigned char f = flagT[base + lane];
    unsigned long long mask = __ballot(f != 0);
    while (mask) {
      int b = __ffsll(mask) - 1;
      mask &= mask - 1;
      size_t e = base + b;
      int mat = (int)(e >> 22);
      int rest = (int)(e & 4194303);
      int j = rest >> 11, i = rest & 2047;
      const u16* Bh = mat == 0 ? BqH : (mat == 1 ? BkH : BvH);
      const u16* Bl = mat == 0 ? BqL : (mat == 1 ? BkL : BvL);
      const u16* xhr = xh + (size_t)i * DD + lane * 32;
      const u16* xlr = xl + (size_t)i * DD + lane * 32;
      const u16* bhr = Bh + (size_t)j * DD + lane * 32;
      const u16* blr = Bl + (size_t)j * DD + lane * 32;
      float u = 0.f;
#pragma unroll
      for (int t = 0; t < 4; ++t) {
        u16x8 a = *(const u16x8*)(xhr + t * 8);
        u16x8 al_ = *(const u16x8*)(xlr + t * 8);
        u16x8 bh_ = *(const u16x8*)(bhr + t * 8);
        u16x8 bl_ = *(const u16x8*)(blr + t * 8);
#pragma unroll
        for (int k2 = 0; k2 < 8; ++k2) {
          float av = bf2f(a[k2]) + bf2f(al_[k2]);
          float bv = bf2f(bh_[k2]) + bf2f(bl_[k2]);
          u = fmaf(av, bv, u);
        }
      }
#pragma unroll
      for (int s = 32; s; s >>= 1) u += __shfl_xor(u, s);
      if (lane == 0) {
        u16* Out2 = mat == 0 ? Sq : (mat == 1 ? Sk : Sv);
        Out2[(size_t)i * DD + j] = (u > 1.0f) ? (u16)0x3F80 : (u16)0;
      }
    }
  }
}

// ---------------- final GEMM: out_pre(bf16) @ Wo -> fp32 ----------------
__global__ __launch_bounds__(256) void k_gemm_out(const u16* __restrict__ A,
                                                  const u16* __restrict__ BT,
                                                  float* __restrict__ C) {
  __shared__ u16 lA[2 * 4096];
  __shared__ u16 lB[2 * 4096];
  int bid = blockIdx.x;
  int swz = (bid & 7) * 32 + (bid >> 3);
  int m0 = (swz >> 4) * 128, n0 = (swz & 15) * 128;
  int tid = threadIdx.x;
  int lane = tid & 63;
  int w = tid >> 6;
  int wr = (w >> 1) * 64, wc = (w & 1) * 64;
  int l15 = lane & 15, g8 = (lane >> 4) * 8;
  int ar0 = tid >> 2, ac0 = (tid & 3) << 3;
  int ar1 = (tid + 256) >> 2, ac1 = (tid & 3) << 3;
  f32x4 zero = {0.f, 0.f, 0.f, 0.f};
  f32x4 acc[4][4];
#pragma unroll
  for (int i = 0; i < 4; ++i)
#pragma unroll
    for (int j = 0; j < 4; ++j) acc[i][j] = zero;

  u16* laBase0 = lA + w * 512;
  u16* laBase1 = lA + 2048 + w * 512;
  u16* lbBase0 = lB + w * 512;
  u16* lbBase1 = lB + 2048 + w * 512;

  auto stage = [&](int buf, int vs) {
    int k0 = vs << 5;
    int bo = buf * 4096;
    GL16(&A[(size_t)(m0 + ar0) * DD + k0 + ac0], laBase0 + bo);
    GL16(&A[(size_t)(m0 + ar1) * DD + k0 + ac1], laBase1 + bo);
    GL16(&BT[(size_t)(n0 + ar0) * DD + k0 + ac0], lbBase0 + bo);
    GL16(&BT[(size_t)(n0 + ar1) * DD + k0 + ac1], lbBase1 + bo);
  };

  stage(0, 0);
  __syncthreads();
  for (int vs = 0; vs < 64; ++vs) {
    int cur = vs & 1;
    if (vs + 1 < 64) stage(cur ^ 1, vs + 1);
    const u16* la = lA + cur * 4096;
    const u16* lb = lB + cur * 4096;
    bf16x8 af[4], bfr[4];
#pragma unroll
    for (int i = 0; i < 4; ++i) af[i] = *(const bf16x8*)&la[(wr + i * 16 + l15) * 32 + g8];
#pragma unroll
    for (int j = 0; j < 4; ++j) bfr[j] = *(const bf16x8*)&lb[(wc + j * 16 + l15) * 32 + g8];
#pragma unroll
    for (int i = 0; i < 4; ++i)
#pragma unroll
      for (int j = 0; j < 4; ++j)
        acc[i][j] = __builtin_amdgcn_mfma_f32_16x16x32_bf16(af[i], bfr[j], acc[i][j], 0, 0, 0);
    __syncthreads();
  }

  int g4 = (lane >> 4) * 4;
#pragma unroll
  for (int i = 0; i < 4; ++i) {
    int row0 = m0 + wr + i * 16 + g4;
#pragma unroll
    for (int j = 0; j < 4; ++j) {
      int col = n0 + wc + j * 16 + l15;
#pragma unroll
      for (int r = 0; r < 4; ++r) C[(size_t)(row0 + r) * DD + col] = acc[i][j][r];
    }
  }
}

// ---------------- flash attention (causal), swapped QK^T ----------------
// block: 8 waves, BQ=128 (16 q-rows/wave), BKV=64. grid: 16 heads x 16 q-blocks.
__global__ __launch_bounds__(512) void k_attn(const u16* __restrict__ rq,
                                              const u16* __restrict__ rk,
                                              const u16* __restrict__ svT,
                                              u16* __restrict__ outp) {
  __shared__ u16 lrk[64 * 136];      // [kv][d] pad 136
  __shared__ u16 lsv[128 * 72];      // [d][kv] pad 72
  __shared__ u16 lP[8 * 16 * 72];    // per-wave P [q][kv] pad 72

  int bid = blockIdx.x;
  int h = bid & 15;
  int i0 = bid >> 4;
  int qb = (i0 & 1) ? (15 - (i0 >> 1)) : (i0 >> 1);  // heavy/light interleave
  int q0 = qb * 128;

  int tid = threadIdx.x;
  int lane = tid & 63;
  int w = tid >> 6;
  int l15 = lane & 15;
  int g = lane >> 4;
  int qw = q0 + w * 16;
  int qpos = qw + l15;
  int pb = w * 1152 + l15 * 72;

  bf16x8 rqf[4];
#pragma unroll
  for (int ks = 0; ks < 4; ++ks)
    rqf[ks] = *(const bf16x8*)&rq[(size_t)qpos * DD + h * 128 + ks * 32 + g * 8];

  f32x4 zero = {0.f, 0.f, 0.f, 0.f};
  f32x4 acc[8];
#pragma unroll
  for (int dt = 0; dt < 8; ++dt) acc[dt] = zero;
  float mrun = -1e30f, lrun = 0.f;

  int nt = (q0 >> 6) + 2;
  for (int t = 0; t < nt; ++t) {
    int kv0 = t << 6;
    // stage rk [64][128] and svT-slice [128][64]
    int r = tid >> 4, c8 = (tid & 15) << 3;
    u16x8 s0 = *(const u16x8*)&rk[(size_t)(kv0 + r) * DD + h * 128 + c8];
    int idx1 = tid + 512;
    int rB = idx1 >> 4, c8B = (idx1 & 15) << 3;
    u16x8 s2 = *(const u16x8*)&rk[(size_t)(kv0 + rB) * DD + h * 128 + c8B];
    int r2 = tid >> 3, d8 = (tid & 7) << 3;
    u16x8 s1 = *(const u16x8*)&svT[(size_t)(h * 128 + r2) * DD + kv0 + d8];
    int r2B = idx1 >> 3, d8B = (idx1 & 7) << 3;
    u16x8 s3 = *(const u16x8*)&svT[(size_t)(h * 128 + r2B) * DD + kv0 + d8B];

    __syncthreads();
    *(u16x8*)&lrk[r * 136 + c8] = s0;
    *(u16x8*)&lrk[rB * 136 + c8B] = s2;
    *(u16x8*)&lsv[r2 * 72 + d8] = s1;
    *(u16x8*)&lsv[r2B * 72 + d8B] = s3;
    __syncthreads();

    bool active = (kv0 <= qw + 15);
    if (active) {
      // S^T[kv][q] = rk @ rq^T
      f32x4 sacc[4];
#pragma unroll
      for (int kt = 0; kt < 4; ++kt) sacc[kt] = zero;
#pragma unroll
      for (int kt = 0; kt < 4; ++kt)
#pragma unroll
        for (int ks = 0; ks < 4; ++ks) {
          bf16x8 a = *(const bf16x8*)&lrk[(kt * 16 + l15) * 136 + ks * 32 + g * 8];
          sacc[kt] = __builtin_amdgcn_mfma_f32_16x16x32_bf16(a, rqf[ks], sacc[kt], 0, 0, 0);
        }
      float p[4][4];
      float mx = -1e30f;
#pragma unroll
      for (int kt = 0; kt < 4; ++kt)
#pragma unroll
        for (int rr = 0; rr < 4; ++rr) {
          int kvpos = kv0 + kt * 16 + g * 4 + rr;
          float sc = sacc[kt][rr] * SCALE_ATTN;
          sc = (kvpos <= qpos) ? sc : -1e30f;
          p[kt][rr] = sc;
          mx = fmaxf(mx, sc);
        }
      mx = fmaxf(mx, __shfl_xor(mx, 16));
      mx = fmaxf(mx, __shfl_xor(mx, 32));
      float mnew = fmaxf(mrun, mx);
      float alpha = __expf(mrun - mnew);
      float rs = 0.f;
#pragma unroll
      for (int kt = 0; kt < 4; ++kt)
#pragma unroll
        for (int rr = 0; rr < 4; ++rr) {
          float e = __expf(p[kt][rr] - mnew);
          p[kt][rr] = e;
          rs += e;
        }
      rs += __shfl_xor(rs, 16);
      rs += __shfl_xor(rs, 32);
      lrun = lrun * alpha + rs;
      mrun = mnew;
      float al[4];
#pragma unroll
      for (int rr = 0; rr < 4; ++rr) al[rr] = __shfl(alpha, (lane & 48) | (g * 4 + rr), 64);
#pragma unroll
      for (int dt = 0; dt < 8; ++dt)
#pragma unroll
        for (int rr = 0; rr < 4; ++rr) acc[dt][rr] *= al[rr];
#pragma unroll
      for (int kt = 0; kt < 4; ++kt) {
        u16x4 pk = {f2bf(p[kt][0]), f2bf(p[kt][1]), f2bf(p[kt][2]), f2bf(p[kt][3])};
        *(u16x4*)&lP[pb + kt * 16 + g * 4] = pk;
      }
    }
    __syncthreads();
    if (active) {
      bf16x8 pa0 = *(const bf16x8*)&lP[pb + g * 8];
      bf16x8 pa1 = *(const bf16x8*)&lP[pb + 32 + g * 8];
#pragma unroll
      for (int dt = 0; dt < 8; ++dt) {
        bf16x8 b0 = *(const bf16x8*)&lsv[(dt * 16 + l15) * 72 + g * 8];
        acc[dt] = __builtin_amdgcn_mfma_f32_16x16x32_bf16(pa0, b0, acc[dt], 0, 0, 0);
        bf16x8 b1 = *(const bf16x8*)&lsv[(dt * 16 + l15) * 72 + 32 + g * 8];
        acc[dt] = __builtin_amdgcn_mfma_f32_16x16x32_bf16(pa1, b1, acc[dt], 0, 0, 0);
      }
    }
  }

  float linv[4];
#pragma unroll
  for (int rr = 0; rr < 4; ++rr)
    linv[rr] = 1.0f / __shfl(lrun, (lane & 48) | (g * 4 + rr), 64);
#pragma unroll
  for (int dt = 0; dt < 8; ++dt)
#pragma unroll
    for (int rr = 0; rr < 4; ++rr) {
      int row = qw + g * 4 + rr;
      outp[(size_t)row * DD + h * 128 + dt * 16 + l15] = f2bf(acc[dt][rr] * linv[rr]);
    }
}

// ---------------- launcher ----------------
extern "C" void kernel_launch(void* const* d_in, const int* in_sizes, int n_in, void* d_out,
                              int out_size, void* d_ws, size_t ws_size, hipStream_t stream) {
  (void)in_sizes;
  (void)n_in;
  (void)out_size;
  const float* x = (const float*)d_in[0];
  const float* Wq = (const float*)d_in[1];
  const float* Wk = (const float*)d_in[2];
  const float* Wv = (const float*)d_in[3];
  const float* Wo = (const float*)d_in[4];
  float* out = (float*)d_out;

  const size_t SZ = (size_t)DD * DD;
  size_t need = 16 * SZ * 2 + 3 * SZ + 2 * (size_t)2048 * 64 * 4;
  if (ws_size < need) return;  // insufficient scratch; fail visibly without corruption

  char* p = (char*)d_ws;
  auto a16 = [&](void) {
    u16* q = (u16*)p;
    p += SZ * 2;
    return q;
  };
  u16* xh = a16();
  u16* xl = a16();
  u16* BqH = a16();
  u16* BqL = a16();
  u16* BkH = a16();
  u16* BkL = a16();
  u16* BvH = a16();
  u16* BvL = a16();
  u16* BoT = a16();
  u16* sq = a16();
  u16* sk = a16();
  u16* sv = a16();
  u16* rq = a16();
  u16* rk = a16();
  u16* svT = a16();
  u16* outp = a16();
  unsigned char* flagT = (unsigned char*)p;
  p += 3 * SZ;
  float* cosT = (float*)p;
  p += (size_t)2048 * 64 * 4;
  float* sinT = (float*)p;

  k_rope_tables<<<512, 256, 0, stream>>>(cosT, sinT);
  k_split_x<<<4096, 256, 0, stream>>>(x, xh, xl);
  k_transpose_split<<<4096, 256, 0, stream>>>(Wq, BqH, BqL);
  k_transpose_split<<<4096, 256, 0, stream>>>(Wk, BkH, BkL);
  k_transpose_split<<<4096, 256, 0, stream>>>(Wv, BvH, BvL);
  k_transpose_split<<<4096, 256, 0, stream>>>(Wo, BoT, (u16*)nullptr);
  k_gemm_qkv<<<dim3(256, 3, 1), 256, 0, stream>>>(xh, BqH, BkH, BvH, sq, sk, sv, flagT);
  k_fixup<<<2048, 256, 0, stream>>>(xh, xl, BqH, BqL, BkH, BkL, BvH, BvL, flagT, sq, sk, sv);
  k_rope_apply<<<8192, 256, 0, stream>>>(sq, sk, cosT, sinT, rq, rk);
  k_transpose_bf16<<<4096, 256, 0, stream>>>(sv, svT);
  k_attn<<<256, 512, 0, stream>>>(rq, rk, svT, outp);
  k_gemm_out<<<256, 256, 0, stream>>>(outp, BoT, out);
}

// Round 5
// 370.233 us; speedup vs baseline: 1.3551x; 1.3551x over previous
//
#include <hip/hip_runtime.h>

typedef unsigned short u16;
typedef unsigned int u32;
typedef u16 u16x4 __attribute__((ext_vector_type(4)));
typedef u16 u16x8 __attribute__((ext_vector_type(8)));
typedef float f32x4 __attribute__((ext_vector_type(4)));
typedef __bf16 bf16x8 __attribute__((ext_vector_type(8)));
typedef _Float16 f16x4 __attribute__((ext_vector_type(4)));
typedef _Float16 f16x8 __attribute__((ext_vector_type(8)));

#define DD 2048
#define SCALE_ATTN 0.08838834764831845f
#define DELTA 0.005f

// async global->LDS, 16B per lane, wave-uniform LDS base (HW: base + lane*16)
#define GL16(g, l)                                                              \
  __builtin_amdgcn_global_load_lds((const __attribute__((address_space(1))) u32*)(g), \
                                   (__attribute__((address_space(3))) u32*)(l), 16, 0, 0)

__device__ __forceinline__ u16 f2bf(float f) {
  u32 u = __float_as_uint(f);
  u32 r = (u + 0x7FFFu + ((u >> 16) & 1u)) >> 16;
  return (u16)r;
}
__device__ __forceinline__ float bf2f(u16 h) { return __uint_as_float(((u32)h) << 16); }

// ---------------- prep kernels ----------------

__global__ void k_rope_tables(float* __restrict__ cosT, float* __restrict__ sinT) {
  int i = blockIdx.x * 256 + threadIdx.x;  // < 2048*64
  int s = i >> 6, j = i & 63;
  float e = (float)(2 * j) / 128.0f;
  float inv = 1.0f / powf(10000.0f, e);
  float fr = (float)s * inv;
  cosT[i] = cosf(fr);
  sinT[i] = sinf(fr);
}

// x fp32 -> fp16 (RTN), 4 elems/thread
__global__ void k_cvt_x(const float* __restrict__ x, _Float16* __restrict__ xf) {
  int i = (blockIdx.x * 256 + threadIdx.x) * 4;
  float4 v = *(const float4*)&x[i];
  f16x4 o = {(_Float16)v.x, (_Float16)v.y, (_Float16)v.z, (_Float16)v.w};
  *(f16x4*)&xf[i] = o;
}

// W [k][n] fp32 -> WT16 [n][k] fp16 + WT32 [n][k] fp32
__global__ void k_transpose_w(const float* __restrict__ W, _Float16* __restrict__ WT16,
                              float* __restrict__ WT32) {
  __shared__ float tile[32][33];
  int bk = blockIdx.x & 63, bn = blockIdx.x >> 6;
  int c = threadIdx.x & 31, r0 = threadIdx.x >> 5;
#pragma unroll
  for (int i = 0; i < 4; ++i) {
    int r = r0 + i * 8;
    tile[r][c] = W[(size_t)(bk * 32 + r) * DD + bn * 32 + c];
  }
  __syncthreads();
#pragma unroll
  for (int i = 0; i < 4; ++i) {
    int r = r0 + i * 8;
    float v = tile[c][r];  // = W[bk*32+c][bn*32+r]
    size_t o = (size_t)(bn * 32 + r) * DD + bk * 32 + c;
    WT16[o] = (_Float16)v;
    WT32[o] = v;
  }
}

// W [k][n] fp32 -> WT [n][k] bf16 (for Wo)
__global__ void k_transpose_bo(const float* __restrict__ W, u16* __restrict__ WhT) {
  __shared__ float tile[32][33];
  int bk = blockIdx.x & 63, bn = blockIdx.x >> 6;
  int c = threadIdx.x & 31, r0 = threadIdx.x >> 5;
#pragma unroll
  for (int i = 0; i < 4; ++i) {
    int r = r0 + i * 8;
    tile[r][c] = W[(size_t)(bk * 32 + r) * DD + bn * 32 + c];
  }
  __syncthreads();
#pragma unroll
  for (int i = 0; i < 4; ++i) {
    int r = r0 + i * 8;
    WhT[(size_t)(bn * 32 + r) * DD + bk * 32 + c] = f2bf(tile[c][r]);
  }
}

__global__ void k_transpose_bf16(const u16* __restrict__ in, u16* __restrict__ out) {
  __shared__ u16 tile[32][33];
  int bk = blockIdx.x & 63, bn = blockIdx.x >> 6;
  int c = threadIdx.x & 31, r0 = threadIdx.x >> 5;
#pragma unroll
  for (int i = 0; i < 4; ++i) {
    int r = r0 + i * 8;
    tile[r][c] = in[(size_t)(bk * 32 + r) * DD + bn * 32 + c];
  }
  __syncthreads();
#pragma unroll
  for (int i = 0; i < 4; ++i) {
    int r = r0 + i * 8;
    out[(size_t)(bn * 32 + r) * DD + bk * 32 + c] = tile[c][r];
  }
}

// in-place RoPE on spike maps (sq,sk read+write; per-thread pairs, no hazard)
__global__ void k_rope_apply(u16* sq, u16* sk, const float* __restrict__ cosT,
                             const float* __restrict__ sinT) {
  int i = blockIdx.x * 256 + threadIdx.x;  // < 2048*16*64
  int s = i >> 10;
  int rest = i & 1023;
  int h = rest >> 6, j = rest & 63;
  size_t base = (size_t)s * DD + h * 128 + j;
  float c = cosT[(s << 6) | j], sn = sinT[(s << 6) | j];
  float a = bf2f(sq[base]), b = bf2f(sq[base + 64]);
  sq[base] = f2bf(a * c - b * sn);
  sq[base + 64] = f2bf(b * c + a * sn);
  a = bf2f(sk[base]);
  b = bf2f(sk[base + 64]);
  sk[base] = f2bf(a * c - b * sn);
  sk[base + 64] = f2bf(b * c + a * sn);
}

// ---------------- QKV GEMM pass 1 (fp16): u ~= x16 @ W16^T ----------------
// fp16 dot error sigma ~4e-4; elements with |u-1| < DELTA (=12.5 sigma) are
// flagged for exact fp32 recompute in k_fixup.
__global__ __launch_bounds__(256) void k_gemm_qkv(
    const _Float16* __restrict__ xf, const _Float16* __restrict__ BqT,
    const _Float16* __restrict__ BkT, const _Float16* __restrict__ BvT, u16* __restrict__ Sq,
    u16* __restrict__ Sk, u16* __restrict__ Sv, unsigned char* __restrict__ flagT) {
  __shared__ u16 lA[2 * 4096];
  __shared__ u16 lB[2 * 4096];

  const _Float16* BT = blockIdx.y == 0 ? BqT : (blockIdx.y == 1 ? BkT : BvT);
  u16* Out = blockIdx.y == 0 ? Sq : (blockIdx.y == 1 ? Sk : Sv);
  unsigned char* flT = flagT + (size_t)blockIdx.y * 4194304;  // [j][i] bytemap

  int bid = blockIdx.x;
  int swz = (bid & 7) * 32 + (bid >> 3);  // XCD-aware swizzle, 256 % 8 == 0
  int m0 = (swz >> 4) * 128, n0 = (swz & 15) * 128;

  int tid = threadIdx.x;
  int lane = tid & 63;
  int w = tid >> 6;
  int wr = (w >> 1) * 64, wc = (w & 1) * 64;
  int l15 = lane & 15, g8 = (lane >> 4) * 8;

  int ar0 = tid >> 2, ac0 = (tid & 3) << 3;          // rows 0..63
  int ar1 = (tid + 256) >> 2, ac1 = (tid & 3) << 3;  // rows 64..127

  f32x4 zero = {0.f, 0.f, 0.f, 0.f};
  f32x4 acc[4][4];
#pragma unroll
  for (int i = 0; i < 4; ++i)
#pragma unroll
    for (int j = 0; j < 4; ++j) acc[i][j] = zero;

  u16* laBase0 = lA + w * 512;
  u16* laBase1 = lA + 2048 + w * 512;
  u16* lbBase0 = lB + w * 512;
  u16* lbBase1 = lB + 2048 + w * 512;

  auto stage = [&](int buf, int vs) {
    int k0 = vs << 5;
    int bo = buf * 4096;
    GL16(&xf[(size_t)(m0 + ar0) * DD + k0 + ac0], laBase0 + bo);
    GL16(&xf[(size_t)(m0 + ar1) * DD + k0 + ac1], laBase1 + bo);
    GL16(&BT[(size_t)(n0 + ar0) * DD + k0 + ac0], lbBase0 + bo);
    GL16(&BT[(size_t)(n0 + ar1) * DD + k0 + ac1], lbBase1 + bo);
  };

  stage(0, 0);
  __syncthreads();  // prologue: buf0 ready
  for (int vs = 0; vs < 64; ++vs) {
    int cur = vs & 1;
    if (vs + 1 < 64) stage(cur ^ 1, vs + 1);  // issue next-tile loads FIRST
    const u16* la = lA + cur * 4096;
    const u16* lb = lB + cur * 4096;
    f16x8 af[4], bfr[4];
#pragma unroll
    for (int i = 0; i < 4; ++i) af[i] = *(const f16x8*)&la[(wr + i * 16 + l15) * 32 + g8];
#pragma unroll
    for (int j = 0; j < 4; ++j) bfr[j] = *(const f16x8*)&lb[(wc + j * 16 + l15) * 32 + g8];
#pragma unroll
    for (int i = 0; i < 4; ++i)
#pragma unroll
      for (int j = 0; j < 4; ++j)
        acc[i][j] = __builtin_amdgcn_mfma_f32_16x16x32_f16(af[i], bfr[j], acc[i][j], 0, 0, 0);
    __syncthreads();  // one vmcnt(0)+barrier per tile, at the END
  }

  int g4 = (lane >> 4) * 4;
#pragma unroll
  for (int i = 0; i < 4; ++i) {
    int row0 = m0 + wr + i * 16 + g4;
#pragma unroll
    for (int j = 0; j < 4; ++j) {
      int col = n0 + wc + j * 16 + l15;
      u32 fw = 0;
#pragma unroll
      for (int r = 0; r < 4; ++r) {
        float u = acc[i][j][r];
        Out[(size_t)(row0 + r) * DD + col] = (u > 1.0f) ? (u16)0x3F80 : (u16)0;
        if (fabsf(u - 1.0f) < DELTA) fw |= (1u << (8 * r));
      }
      *(u32*)&flT[(size_t)col * 2048 + row0] = fw;  // row0 % 4 == 0, aligned
    }
  }
}

// ---------------- fixup: exact fp32 recompute of borderline spikes ----------
// Scan bytemap 64B/wave; for each flagged (mat,j,i) all 64 lanes do the exact
// fp32 dot u = x[i,:] . WT32[j,:] and overwrite the spike.
#define NCHUNK 196608  // 3*2048*2048/64
__global__ __launch_bounds__(256) void k_fixup(
    const float* __restrict__ x, const float* __restrict__ WqT, const float* __restrict__ WkT,
    const float* __restrict__ WvT, const unsigned char* __restrict__ flagT, u16* __restrict__ Sq,
    u16* __restrict__ Sk, u16* __restrict__ Sv) {
  int wid = (blockIdx.x * 256 + threadIdx.x) >> 6;
  int lane = threadIdx.x & 63;
  for (int c = wid; c < NCHUNK; c += 8192) {
    size_t base = (size_t)c << 6;
    unsigned char f = flagT[base + lane];
    unsigned long long mask = __ballot(f != 0);
    while (mask) {
      int b = __ffsll(mask) - 1;
      mask &= mask - 1;
      size_t e = base + b;
      int mat = (int)(e >> 22);
      int rest = (int)(e & 4194303);
      int j = rest >> 11, i = rest & 2047;
      const float* WT = mat == 0 ? WqT : (mat == 1 ? WkT : WvT);
      const float4* xr = (const float4*)(x + (size_t)i * DD + lane * 32);
      const float4* wr_ = (const float4*)(WT + (size_t)j * DD + lane * 32);
      float u = 0.f;
#pragma unroll
      for (int t = 0; t < 8; ++t) {
        float4 a = xr[t];
        float4 bv = wr_[t];
        u = fmaf(a.x, bv.x, u);
        u = fmaf(a.y, bv.y, u);
        u = fmaf(a.z, bv.z, u);
        u = fmaf(a.w, bv.w, u);
      }
#pragma unroll
      for (int s = 32; s; s >>= 1) u += __shfl_xor(u, s);
      if (lane == 0) {
        u16* Out2 = mat == 0 ? Sq : (mat == 1 ? Sk : Sv);
        Out2[(size_t)i * DD + j] = (u > 1.0f) ? (u16)0x3F80 : (u16)0;
      }
    }
  }
}

// ---------------- final GEMM: out_pre(bf16) @ Wo -> fp32 ----------------
__global__ __launch_bounds__(256) void k_gemm_out(const u16* __restrict__ A,
                                                  const u16* __restrict__ BT,
                                                  float* __restrict__ C) {
  __shared__ u16 lA[2 * 4096];
  __shared__ u16 lB[2 * 4096];
  int bid = blockIdx.x;
  int swz = (bid & 7) * 32 + (bid >> 3);
  int m0 = (swz >> 4) * 128, n0 = (swz & 15) * 128;
  int tid = threadIdx.x;
  int lane = tid & 63;
  int w = tid >> 6;
  int wr = (w >> 1) * 64, wc = (w & 1) * 64;
  int l15 = lane & 15, g8 = (lane >> 4) * 8;
  int ar0 = tid >> 2, ac0 = (tid & 3) << 3;
  int ar1 = (tid + 256) >> 2, ac1 = (tid & 3) << 3;
  f32x4 zero = {0.f, 0.f, 0.f, 0.f};
  f32x4 acc[4][4];
#pragma unroll
  for (int i = 0; i < 4; ++i)
#pragma unroll
    for (int j = 0; j < 4; ++j) acc[i][j] = zero;

  u16* laBase0 = lA + w * 512;
  u16* laBase1 = lA + 2048 + w * 512;
  u16* lbBase0 = lB + w * 512;
  u16* lbBase1 = lB + 2048 + w * 512;

  auto stage = [&](int buf, int vs) {
    int k0 = vs << 5;
    int bo = buf * 4096;
    GL16(&A[(size_t)(m0 + ar0) * DD + k0 + ac0], laBase0 + bo);
    GL16(&A[(size_t)(m0 + ar1) * DD + k0 + ac1], laBase1 + bo);
    GL16(&BT[(size_t)(n0 + ar0) * DD + k0 + ac0], lbBase0 + bo);
    GL16(&BT[(size_t)(n0 + ar1) * DD + k0 + ac1], lbBase1 + bo);
  };

  stage(0, 0);
  __syncthreads();
  for (int vs = 0; vs < 64; ++vs) {
    int cur = vs & 1;
    if (vs + 1 < 64) stage(cur ^ 1, vs + 1);
    const u16* la = lA + cur * 4096;
    const u16* lb = lB + cur * 4096;
    bf16x8 af[4], bfr[4];
#pragma unroll
    for (int i = 0; i < 4; ++i) af[i] = *(const bf16x8*)&la[(wr + i * 16 + l15) * 32 + g8];
#pragma unroll
    for (int j = 0; j < 4; ++j) bfr[j] = *(const bf16x8*)&lb[(wc + j * 16 + l15) * 32 + g8];
#pragma unroll
    for (int i = 0; i < 4; ++i)
#pragma unroll
      for (int j = 0; j < 4; ++j)
        acc[i][j] = __builtin_amdgcn_mfma_f32_16x16x32_bf16(af[i], bfr[j], acc[i][j], 0, 0, 0);
    __syncthreads();
  }

  int g4 = (lane >> 4) * 4;
#pragma unroll
  for (int i = 0; i < 4; ++i) {
    int row0 = m0 + wr + i * 16 + g4;
#pragma unroll
    for (int j = 0; j < 4; ++j) {
      int col = n0 + wc + j * 16 + l15;
#pragma unroll
      for (int r = 0; r < 4; ++r) C[(size_t)(row0 + r) * DD + col] = acc[i][j][r];
    }
  }
}

// ---------------- flash attention (causal), swapped QK^T ----------------
// block: 8 waves, BQ=128 (16 q-rows/wave), BKV=64. grid: 16 heads x 16 q-blocks.
__global__ __launch_bounds__(512) void k_attn(const u16* __restrict__ rq,
                                              const u16* __restrict__ rk,
                                              const u16* __restrict__ svT,
                                              u16* __restrict__ outp) {
  __shared__ u16 lrk[64 * 136];      // [kv][d] pad 136
  __shared__ u16 lsv[128 * 72];      // [d][kv] pad 72
  __shared__ u16 lP[8 * 16 * 72];    // per-wave P [q][kv] pad 72

  int bid = blockIdx.x;
  int h = bid & 15;
  int i0 = bid >> 4;
  int qb = (i0 & 1) ? (15 - (i0 >> 1)) : (i0 >> 1);  // heavy/light interleave
  int q0 = qb * 128;

  int tid = threadIdx.x;
  int lane = tid & 63;
  int w = tid >> 6;
  int l15 = lane & 15;
  int g = lane >> 4;
  int qw = q0 + w * 16;
  int qpos = qw + l15;
  int pb = w * 1152 + l15 * 72;

  bf16x8 rqf[4];
#pragma unroll
  for (int ks = 0; ks < 4; ++ks)
    rqf[ks] = *(const bf16x8*)&rq[(size_t)qpos * DD + h * 128 + ks * 32 + g * 8];

  f32x4 zero = {0.f, 0.f, 0.f, 0.f};
  f32x4 acc[8];
#pragma unroll
  for (int dt = 0; dt < 8; ++dt) acc[dt] = zero;
  float mrun = -1e30f, lrun = 0.f;

  int nt = (q0 >> 6) + 2;
  for (int t = 0; t < nt; ++t) {
    int kv0 = t << 6;
    // stage rk [64][128] and svT-slice [128][64]
    int r = tid >> 4, c8 = (tid & 15) << 3;
    u16x8 s0 = *(const u16x8*)&rk[(size_t)(kv0 + r) * DD + h * 128 + c8];
    int idx1 = tid + 512;
    int rB = idx1 >> 4, c8B = (idx1 & 15) << 3;
    u16x8 s2 = *(const u16x8*)&rk[(size_t)(kv0 + rB) * DD + h * 128 + c8B];
    int r2 = tid >> 3, d8 = (tid & 7) << 3;
    u16x8 s1 = *(const u16x8*)&svT[(size_t)(h * 128 + r2) * DD + kv0 + d8];
    int r2B = idx1 >> 3, d8B = (idx1 & 7) << 3;
    u16x8 s3 = *(const u16x8*)&svT[(size_t)(h * 128 + r2B) * DD + kv0 + d8B];

    __syncthreads();
    *(u16x8*)&lrk[r * 136 + c8] = s0;
    *(u16x8*)&lrk[rB * 136 + c8B] = s2;
    *(u16x8*)&lsv[r2 * 72 + d8] = s1;
    *(u16x8*)&lsv[r2B * 72 + d8B] = s3;
    __syncthreads();

    bool active = (kv0 <= qw + 15);
    if (active) {
      // S^T[kv][q] = rk @ rq^T
      f32x4 sacc[4];
#pragma unroll
      for (int kt = 0; kt < 4; ++kt) sacc[kt] = zero;
#pragma unroll
      for (int kt = 0; kt < 4; ++kt)
#pragma unroll
        for (int ks = 0; ks < 4; ++ks) {
          bf16x8 a = *(const bf16x8*)&lrk[(kt * 16 + l15) * 136 + ks * 32 + g * 8];
          sacc[kt] = __builtin_amdgcn_mfma_f32_16x16x32_bf16(a, rqf[ks], sacc[kt], 0, 0, 0);
        }
      float p[4][4];
      float mx = -1e30f;
#pragma unroll
      for (int kt = 0; kt < 4; ++kt)
#pragma unroll
        for (int rr = 0; rr < 4; ++rr) {
          int kvpos = kv0 + kt * 16 + g * 4 + rr;
          float sc = sacc[kt][rr] * SCALE_ATTN;
          sc = (kvpos <= qpos) ? sc : -1e30f;
          p[kt][rr] = sc;
          mx = fmaxf(mx, sc);
        }
      mx = fmaxf(mx, __shfl_xor(mx, 16));
      mx = fmaxf(mx, __shfl_xor(mx, 32));
      float mnew = fmaxf(mrun, mx);
      float alpha = __expf(mrun - mnew);
      float rs = 0.f;
#pragma unroll
      for (int kt = 0; kt < 4; ++kt)
#pragma unroll
        for (int rr = 0; rr < 4; ++rr) {
          float e = __expf(p[kt][rr] - mnew);
          p[kt][rr] = e;
          rs += e;
        }
      rs += __shfl_xor(rs, 16);
      rs += __shfl_xor(rs, 32);
      lrun = lrun * alpha + rs;
      mrun = mnew;
      float al[4];
#pragma unroll
      for (int rr = 0; rr < 4; ++rr) al[rr] = __shfl(alpha, (lane & 48) | (g * 4 + rr), 64);
#pragma unroll
      for (int dt = 0; dt < 8; ++dt)
#pragma unroll
        for (int rr = 0; rr < 4; ++rr) acc[dt][rr] *= al[rr];
#pragma unroll
      for (int kt = 0; kt < 4; ++kt) {
        u16x4 pk = {f2bf(p[kt][0]), f2bf(p[kt][1]), f2bf(p[kt][2]), f2bf(p[kt][3])};
        *(u16x4*)&lP[pb + kt * 16 + g * 4] = pk;
      }
    }
    __syncthreads();
    if (active) {
      bf16x8 pa0 = *(const bf16x8*)&lP[pb + g * 8];
      bf16x8 pa1 = *(const bf16x8*)&lP[pb + 32 + g * 8];
#pragma unroll
      for (int dt = 0; dt < 8; ++dt) {
        bf16x8 b0 = *(const bf16x8*)&lsv[(dt * 16 + l15) * 72 + g * 8];
        acc[dt] = __builtin_amdgcn_mfma_f32_16x16x32_bf16(pa0, b0, acc[dt], 0, 0, 0);
        bf16x8 b1 = *(const bf16x8*)&lsv[(dt * 16 + l15) * 72 + 32 + g * 8];
        acc[dt] = __builtin_amdgcn_mfma_f32_16x16x32_bf16(pa1, b1, acc[dt], 0, 0, 0);
      }
    }
  }

  float linv[4];
#pragma unroll
  for (int rr = 0; rr < 4; ++rr)
    linv[rr] = 1.0f / __shfl(lrun, (lane & 48) | (g * 4 + rr), 64);
#pragma unroll
  for (int dt = 0; dt < 8; ++dt)
#pragma unroll
    for (int rr = 0; rr < 4; ++rr) {
      int row = qw + g * 4 + rr;
      outp[(size_t)row * DD + h * 128 + dt * 16 + l15] = f2bf(acc[dt][rr] * linv[rr]);
    }
}

// ---------------- launcher ----------------
extern "C" void kernel_launch(void* const* d_in, const int* in_sizes, int n_in, void* d_out,
                              int out_size, void* d_ws, size_t ws_size, hipStream_t stream) {
  (void)in_sizes;
  (void)n_in;
  (void)out_size;
  const float* x = (const float*)d_in[0];
  const float* Wq = (const float*)d_in[1];
  const float* Wk = (const float*)d_in[2];
  const float* Wv = (const float*)d_in[3];
  const float* Wo = (const float*)d_in[4];
  float* out = (float*)d_out;

  const size_t SZ = (size_t)DD * DD;
  // xf + 3*WT16 + BoT + 5 bf16 maps = 10 x (SZ*2); 3*WT32 = 3*(SZ*4); flags 3*SZ; tables.
  size_t need = 35 * SZ + 2 * (size_t)2048 * 64 * 4;  // == R3's proven footprint
  if (ws_size < need) return;  // insufficient scratch; fail visibly without corruption

  char* p = (char*)d_ws;
  auto a2 = [&](void) {  // SZ 16-bit elems
    void* q = (void*)p;
    p += SZ * 2;
    return q;
  };
  _Float16* xf = (_Float16*)a2();
  _Float16* WqT16 = (_Float16*)a2();
  _Float16* WkT16 = (_Float16*)a2();
  _Float16* WvT16 = (_Float16*)a2();
  u16* BoT = (u16*)a2();
  u16* sq = (u16*)a2();
  u16* sk = (u16*)a2();
  u16* sv = (u16*)a2();
  u16* svT = (u16*)a2();
  u16* outp = (u16*)a2();
  float* WqT32 = (float*)p;
  p += SZ * 4;
  float* WkT32 = (float*)p;
  p += SZ * 4;
  float* WvT32 = (float*)p;
  p += SZ * 4;
  unsigned char* flagT = (unsigned char*)p;
  p += 3 * SZ;
  float* cosT = (float*)p;
  p += (size_t)2048 * 64 * 4;
  float* sinT = (float*)p;

  k_rope_tables<<<512, 256, 0, stream>>>(cosT, sinT);
  k_cvt_x<<<4096, 256, 0, stream>>>(x, xf);
  k_transpose_w<<<4096, 256, 0, stream>>>(Wq, WqT16, WqT32);
  k_transpose_w<<<4096, 256, 0, stream>>>(Wk, WkT16, WkT32);
  k_transpose_w<<<4096, 256, 0, stream>>>(Wv, WvT16, WvT32);
  k_transpose_bo<<<4096, 256, 0, stream>>>(Wo, BoT);
  k_gemm_qkv<<<dim3(256, 3, 1), 256, 0, stream>>>(xf, WqT16, WkT16, WvT16, sq, sk, sv, flagT);
  k_fixup<<<2048, 256, 0, stream>>>(x, WqT32, WkT32, WvT32, flagT, sq, sk, sv);
  k_rope_apply<<<8192, 256, 0, stream>>>(sq, sk, cosT, sinT);  // in-place: sq->rq, sk->rk
  k_transpose_bf16<<<4096, 256, 0, stream>>>(sv, svT);
  k_attn<<<256, 512, 0, stream>>>(sq, sk, svT, outp);
  k_gemm_out<<<256, 256, 0, stream>>>(outp, BoT, out);
}